// Round 3
// baseline (152.278 us; speedup 1.0000x reference)
//
#include <hip/hip_runtime.h>
#include <hip/hip_bf16.h>
#include <stdint.h>

// Q8_0 dequant linear: y = x @ W^T + bias.  M=N=K=4096.
// (1) x fp32->bf16, (2) W dequant->bf16, (3) 256x256-tile 8-phase bf16 MFMA GEMM
//     m201 template: counted vmcnt, XOR-swizzled LDS, setprio, 2 K-tiles/iter
//     (static buffers), all LDS fragment reads hoisted to phases 0-1 so the
//     current-buffer stages in phases 2-3 cannot race the reads.

#define M_DIM 4096
#define N_DIM 4096
#define K_DIM 4096
#define NB_SC 128

#define BM 256
#define BN 256
#define BK 64
#define NT (K_DIM / BK)   // 64 K-tiles

typedef __attribute__((ext_vector_type(8))) short bf16x8;
typedef __attribute__((ext_vector_type(4))) float f32x4;

__device__ __forceinline__ unsigned short f2bf(float f) {
  unsigned int u = __float_as_uint(f);
  u += 0x7fffu + ((u >> 16) & 1u);
  return (unsigned short)(u >> 16);
}

__device__ __forceinline__ void gload_lds16(const void* gsrc, void* ldsdst) {
  __builtin_amdgcn_global_load_lds(
      (__attribute__((address_space(1))) void*)(uintptr_t)gsrc,
      (__attribute__((address_space(3))) void*)(uint32_t)(uintptr_t)ldsdst,
      16, 0, 0);
}

// ---------------- prep kernels ----------------

__global__ void cvt_x_kernel(const float* __restrict__ x, unsigned short* __restrict__ xb) {
  const size_t total8 = (size_t)M_DIM * K_DIM / 8;
  for (size_t t = (size_t)blockIdx.x * blockDim.x + threadIdx.x; t < total8;
       t += (size_t)gridDim.x * blockDim.x) {
    size_t base = t * 8;
    const float4* p = (const float4*)(x + base);
    float4 a = p[0], b = p[1];
    union { unsigned short u[8]; uint4 v; } r;
    r.u[0] = f2bf(a.x); r.u[1] = f2bf(a.y); r.u[2] = f2bf(a.z); r.u[3] = f2bf(a.w);
    r.u[4] = f2bf(b.x); r.u[5] = f2bf(b.y); r.u[6] = f2bf(b.z); r.u[7] = f2bf(b.w);
    *(uint4*)(xb + base) = r.v;
  }
}

__global__ void dequant_kernel(const int* __restrict__ q, const float* __restrict__ sc,
                               unsigned short* __restrict__ wb) {
  const size_t total8 = (size_t)N_DIM * K_DIM / 8;
  for (size_t t = (size_t)blockIdx.x * blockDim.x + threadIdx.x; t < total8;
       t += (size_t)gridDim.x * blockDim.x) {
    size_t base = t * 8;
    int o = (int)(base >> 12);
    int i = (int)(base & 4095);
    float s = sc[(o << 7) + (i >> 5)];
    const int4* qp = (const int4*)(q + base);
    int4 q0 = qp[0], q1 = qp[1];
    union { unsigned short u[8]; uint4 v; } r;
    r.u[0] = f2bf((float)q0.x * s); r.u[1] = f2bf((float)q0.y * s);
    r.u[2] = f2bf((float)q0.z * s); r.u[3] = f2bf((float)q0.w * s);
    r.u[4] = f2bf((float)q1.x * s); r.u[5] = f2bf((float)q1.y * s);
    r.u[6] = f2bf((float)q1.z * s); r.u[7] = f2bf((float)q1.w * s);
    *(uint4*)(wb + base) = r.v;
  }
}

// ---------------- 256x256 8-phase GEMM ----------------
// LDS tile [256][64] bf16, 128B rows = 8 x 16B granules. Logical granule g of
// row r stored at granule g^(r&7); gload_lds dest linear, source pre-permuted.

__device__ __forceinline__ bf16x8 lds_frag(const unsigned short* t, int r, int k0) {
  return *(const bf16x8*)(t + r * 64 + ((((k0) >> 3) ^ (r & 7)) << 3));
}

__device__ __forceinline__ void stage_half(const unsigned short* __restrict__ g,
                                           unsigned short* lds, int hr0, int row0,
                                           int ktT, int w, int l) {
#pragma unroll
  for (int j = 0; j < 2; ++j) {
    const int rbase = hr0 + w * 16 + j * 8;
    const int r = rbase + (l >> 3);
    const int k = ((l & 7) ^ (l >> 3)) << 3;
    gload_lds16(g + (size_t)(row0 + r) * K_DIM + ktT + k, lds + rbase * 64);
  }
}

__device__ __forceinline__ void read_a(const unsigned short* Ac, int r0, int frow, int fk,
                                       bf16x8 (&af)[2][2]) {
#pragma unroll
  for (int q = 0; q < 2; ++q)
#pragma unroll
    for (int kk = 0; kk < 2; ++kk)
      af[q][kk] = lds_frag(Ac, r0 + q * 16 + frow, kk * 32 + fk);
}

__device__ __forceinline__ void mfma_quad(const bf16x8 (&af)[2][2], const bf16x8 (&bf)[4][2],
                                          f32x4 (&acc)[8][4], int q0) {
  __builtin_amdgcn_s_setprio(1);
#pragma unroll
  for (int q = 0; q < 2; ++q)
#pragma unroll
    for (int ni = 0; ni < 4; ++ni)
#pragma unroll
      for (int kk = 0; kk < 2; ++kk)
        acc[q0 + q][ni] =
            __builtin_amdgcn_mfma_f32_16x16x32_bf16(af[q][kk], bf[ni][kk], acc[q0 + q][ni], 0, 0, 0);
  __builtin_amdgcn_s_setprio(0);
}

template <int BUF>
__device__ __forceinline__ void ktile(const unsigned short* __restrict__ A,
                                      const unsigned short* __restrict__ B,
                                      unsigned short* AsB, unsigned short* BsB,
                                      int t, int bm0, int bn0, int w, int l,
                                      int wm, int wn, int frow, int fk,
                                      f32x4 (&acc)[8][4]) {
  const unsigned short* Ac = AsB + BUF * (BM * BK);
  const unsigned short* Bc = BsB + BUF * (BN * BK);
  unsigned short* Aw = AsB + BUF * (BM * BK);
  unsigned short* Bw = BsB + BUF * (BN * BK);
  unsigned short* An = AsB + (BUF ^ 1) * (BM * BK);

  bf16x8 bfrag[4][2];
  bf16x8 a0[2][2], a1[2][2], a2[2][2], a3[2][2];

  // phase 0: read all B (8) + A q0,q1 (8); stage A1(t+1) -> other buffer (safe)
#pragma unroll
  for (int ni = 0; ni < 4; ++ni)
#pragma unroll
    for (int kk = 0; kk < 2; ++kk)
      bfrag[ni][kk] = lds_frag(Bc, wn * 64 + ni * 16 + frow, kk * 32 + fk);
  read_a(Ac, wm * 128 + 0, frow, fk, a0);
  read_a(Ac, wm * 128 + 32, frow, fk, a1);
  if (t + 1 < NT) stage_half(A, An, 128, bm0, (t + 1) * BK, w, l);
  __builtin_amdgcn_s_barrier();
  mfma_quad(a0, bfrag, acc, 0);
  __builtin_amdgcn_s_barrier();

  // phase 1: read A q2,q3; stage B0(t+2) (B reads all completed in phase 0)
  read_a(Ac, wm * 128 + 64, frow, fk, a2);
  read_a(Ac, wm * 128 + 96, frow, fk, a3);
  if (t + 2 < NT) stage_half(B, Bw, 0, bn0, (t + 2) * BK, w, l);
  __builtin_amdgcn_s_barrier();
  mfma_quad(a1, bfrag, acc, 2);
  __builtin_amdgcn_s_barrier();

  // phase 2: stage B1(t+2); compute quad a3 (its lgkm wait implies a2's reads
  // also completed -> phase-3's A0 stage cannot race any A read)
  if (t + 2 < NT) stage_half(B, Bw, 128, bn0, (t + 2) * BK, w, l);
  __builtin_amdgcn_s_barrier();
  mfma_quad(a3, bfrag, acc, 6);
  __builtin_amdgcn_s_barrier();

  // phase 3: stage A0(t+2); compute quad a2; counted vmcnt at tile boundary
  if (t + 2 < NT) stage_half(A, Aw, 0, bm0, (t + 2) * BK, w, l);
  __builtin_amdgcn_s_barrier();
  mfma_quad(a2, bfrag, acc, 4);
  if (t < NT - 2)
    asm volatile("s_waitcnt vmcnt(6)" ::: "memory");  // t+1 landed; t+2's 3 halves in flight
  else
    asm volatile("s_waitcnt vmcnt(0)" ::: "memory");
  __builtin_amdgcn_s_barrier();
}

__global__ __launch_bounds__(512, 2) void gemm256(const unsigned short* __restrict__ A,
                                                  const unsigned short* __restrict__ B,
                                                  const float* __restrict__ bias,
                                                  float* __restrict__ C) {
  __shared__ unsigned short AsB[2 * BM * BK];   // 64 KiB
  __shared__ unsigned short BsB[2 * BN * BK];   // 64 KiB

  const int tid = threadIdx.x;
  const int w = tid >> 6;
  const int l = tid & 63;
  const int wm = w >> 2;
  const int wn = w & 3;
  const int frow = l & 15;
  const int fk = (l >> 4) * 8;

  const int bid = blockIdx.x;
  const int cpx = gridDim.x >> 3;
  const int swz = (bid & 7) * cpx + (bid >> 3);
  const int bm0 = (swz >> 4) * BM;
  const int bn0 = (swz & 15) * BN;

  f32x4 acc[8][4] = {};

  // Prologue: tile0 {B0,B1,A0,A1} -> buf0; tile1 {B0,B1,A0} -> buf1.
  stage_half(B, BsB, 0, bn0, 0, w, l);
  stage_half(B, BsB, 128, bn0, 0, w, l);
  stage_half(A, AsB, 0, bm0, 0, w, l);
  stage_half(A, AsB, 128, bm0, 0, w, l);
  asm volatile("s_waitcnt vmcnt(4)" ::: "memory");
  stage_half(B, BsB + BN * BK, 0, bn0, BK, w, l);
  stage_half(B, BsB + BN * BK, 128, bn0, BK, w, l);
  stage_half(A, AsB + BM * BK, 0, bm0, BK, w, l);
  asm volatile("s_waitcnt vmcnt(6)" ::: "memory");   // tile0 fully landed
  __builtin_amdgcn_s_barrier();

  for (int t = 0; t < NT; t += 2) {
    ktile<0>(A, B, AsB, BsB, t,     bm0, bn0, w, l, wm, wn, frow, fk, acc);
    ktile<1>(A, B, AsB, BsB, t + 1, bm0, bn0, w, l, wm, wn, frow, fk, acc);
  }

  // Epilogue: C/D layout col=lane&15 (n), row=(lane>>4)*4+r (m)
#pragma unroll
  for (int ni = 0; ni < 4; ++ni) {
    int n = bn0 + wn * 64 + ni * 16 + (l & 15);
    float bv = bias[n];
#pragma unroll
    for (int mi = 0; mi < 8; ++mi) {
      int mbase = bm0 + wm * 128 + mi * 16 + (l >> 4) * 4;
#pragma unroll
      for (int r = 0; r < 4; ++r)
        C[(size_t)(mbase + r) * N_DIM + n] = acc[mi][ni][r] + bv;
    }
  }
}

// ---------------- naive fallback ----------------

__global__ void naive_kernel(const float* __restrict__ x, const int* __restrict__ q,
                             const float* __restrict__ sc, const float* __restrict__ bias,
                             float* __restrict__ out) {
  size_t idx = (size_t)blockIdx.x * blockDim.x + threadIdx.x;
  if (idx >= (size_t)M_DIM * N_DIM) return;
  int n = (int)(idx & (N_DIM - 1));
  size_t m = idx >> 12;
  float acc = 0.f;
  for (int k = 0; k < K_DIM; k += 32) {
    float s = sc[n * NB_SC + (k >> 5)];
    float part = 0.f;
    for (int j = 0; j < 32; ++j)
      part += x[m * K_DIM + k + j] * (float)q[(size_t)n * K_DIM + k + j];
    acc += part * s;
  }
  out[idx] = acc + bias[n];
}

// ---------------- launch ----------------

extern "C" void kernel_launch(void* const* d_in, const int* in_sizes, int n_in,
                              void* d_out, int out_size, void* d_ws, size_t ws_size,
                              hipStream_t stream) {
  const float* x    = (const float*)d_in[0];
  const int*   q    = (const int*)d_in[1];
  const float* sc   = (const float*)d_in[2];
  const float* bias = (const float*)d_in[3];
  float* out = (float*)d_out;

  const size_t elems = (size_t)M_DIM * K_DIM;
  const size_t need  = 2 * elems * sizeof(unsigned short);

  if (ws_size >= need) {
    unsigned short* xb = (unsigned short*)d_ws;
    unsigned short* wb = xb + elems;
    hipLaunchKernelGGL(cvt_x_kernel,   dim3(2048), dim3(256), 0, stream, x, xb);
    hipLaunchKernelGGL(dequant_kernel, dim3(2048), dim3(256), 0, stream, q, sc, wb);
    hipLaunchKernelGGL(gemm256, dim3((M_DIM / BM) * (N_DIM / BN)), dim3(512), 0, stream,
                       xb, wb, bias, out);
  } else {
    hipLaunchKernelGGL(naive_kernel, dim3((M_DIM * N_DIM) / 256), dim3(256), 0, stream,
                       x, q, sc, bias, out);
  }
}

// Round 4
// 143.428 us; speedup vs baseline: 1.0617x; 1.0617x over previous
//
#include <hip/hip_runtime.h>
#include <hip/hip_bf16.h>
#include <stdint.h>

// Q8_0 dequant linear: y = x @ W^T + bias.  M=N=K=4096.
// (1) fused prep: x fp32->bf16 and W dequant->bf16  (one launch)
// (2) 256x256-tile 4-phase/K-tile bf16 MFMA GEMM (m201 template):
//     counted vmcnt, XOR-swizzled LDS (0 conflicts), setprio, barrier->lgkmcnt(0)->MFMA,
//     race-free staging (every staged region is read-complete one barrier earlier),
//     lane-const + scalar-offset stage addressing, peeled tail (branch-free main loop).

#define M_DIM 4096
#define N_DIM 4096
#define K_DIM 4096
#define NB_SC 128

#define BM 256
#define BN 256
#define BK 64
#define NT (K_DIM / BK)   // 64 K-tiles

typedef __attribute__((ext_vector_type(8))) short bf16x8;
typedef __attribute__((ext_vector_type(4))) float f32x4;

__device__ __forceinline__ unsigned short f2bf(float f) {
  unsigned int u = __float_as_uint(f);
  u += 0x7fffu + ((u >> 16) & 1u);
  return (unsigned short)(u >> 16);
}

__device__ __forceinline__ void gload_lds16(const void* gsrc, void* ldsdst) {
  __builtin_amdgcn_global_load_lds(
      (__attribute__((address_space(1))) void*)(uintptr_t)gsrc,
      (__attribute__((address_space(3))) void*)(uint32_t)(uintptr_t)ldsdst,
      16, 0, 0);
}

// ---------------- fused prep kernel ----------------

__global__ void prep_kernel(const float* __restrict__ x, const int* __restrict__ q,
                            const float* __restrict__ sc,
                            unsigned short* __restrict__ xb, unsigned short* __restrict__ wb) {
  const size_t total8 = (size_t)M_DIM * K_DIM / 8;
  const int half = gridDim.x >> 1;
  if (blockIdx.x < half) {
    for (size_t t = (size_t)blockIdx.x * blockDim.x + threadIdx.x; t < total8;
         t += (size_t)half * blockDim.x) {
      size_t base = t * 8;
      const float4* p = (const float4*)(x + base);
      float4 a = p[0], b = p[1];
      union { unsigned short u[8]; uint4 v; } r;
      r.u[0] = f2bf(a.x); r.u[1] = f2bf(a.y); r.u[2] = f2bf(a.z); r.u[3] = f2bf(a.w);
      r.u[4] = f2bf(b.x); r.u[5] = f2bf(b.y); r.u[6] = f2bf(b.z); r.u[7] = f2bf(b.w);
      *(uint4*)(xb + base) = r.v;
    }
  } else {
    for (size_t t = (size_t)(blockIdx.x - half) * blockDim.x + threadIdx.x; t < total8;
         t += (size_t)half * blockDim.x) {
      size_t base = t * 8;
      int o = (int)(base >> 12);
      int i = (int)(base & 4095);
      float s = sc[(o << 7) + (i >> 5)];
      const int4* qp = (const int4*)(q + base);
      int4 q0 = qp[0], q1 = qp[1];
      union { unsigned short u[8]; uint4 v; } r;
      r.u[0] = f2bf((float)q0.x * s); r.u[1] = f2bf((float)q0.y * s);
      r.u[2] = f2bf((float)q0.z * s); r.u[3] = f2bf((float)q0.w * s);
      r.u[4] = f2bf((float)q1.x * s); r.u[5] = f2bf((float)q1.y * s);
      r.u[6] = f2bf((float)q1.z * s); r.u[7] = f2bf((float)q1.w * s);
      *(uint4*)(wb + base) = r.v;
    }
  }
}

// ---------------- 256x256 GEMM ----------------
// LDS tile [256][64] bf16, 128B rows = 8 x 16B granules. Logical granule g of
// row r stored at granule g^(r&7); gload_lds dest linear, source pre-permuted.

__device__ __forceinline__ bf16x8 lds_frag(const unsigned short* t, int r, int k0) {
  return *(const bf16x8*)(t + r * 64 + ((((k0) >> 3) ^ (r & 7)) << 3));
}

// pX = X + (row-panel-base + w*16 + (l>>3))*K + ((l&7)^(l>>3))*8   (lane-const)
__device__ __forceinline__ void stage_half(const unsigned short* __restrict__ pX,
                                           unsigned short* lds, int hr0, int kt, int w) {
#pragma unroll
  for (int j = 0; j < 2; ++j) {
    gload_lds16(pX + (size_t)(hr0 + j * 8) * K_DIM + kt,
                lds + (hr0 + w * 16 + j * 8) * 64);
  }
}

__device__ __forceinline__ void read_a(const unsigned short* Ac, int r0, int frow, int fk,
                                       bf16x8 (&af)[2][2]) {
#pragma unroll
  for (int q = 0; q < 2; ++q)
#pragma unroll
    for (int kk = 0; kk < 2; ++kk)
      af[q][kk] = lds_frag(Ac, r0 + q * 16 + frow, kk * 32 + fk);
}

__device__ __forceinline__ void mfma_quad(const bf16x8 (&af)[2][2], const bf16x8 (&bf)[4][2],
                                          f32x4 (&acc)[8][4], int q0) {
  __builtin_amdgcn_s_setprio(1);
#pragma unroll
  for (int q = 0; q < 2; ++q)
#pragma unroll
    for (int ni = 0; ni < 4; ++ni)
#pragma unroll
      for (int kk = 0; kk < 2; ++kk)
        acc[q0 + q][ni] =
            __builtin_amdgcn_mfma_f32_16x16x32_bf16(af[q][kk], bf[ni][kk], acc[q0 + q][ni], 0, 0, 0);
  __builtin_amdgcn_s_setprio(0);
}

// MODE: 0 = steady state (all stages, vmcnt(6))
//       1 = t == NT-2  (stage A1(t+1) only, vmcnt(0) drain)
//       2 = t == NT-1  (no stages, no vmcnt)
template <int BUF, int MODE>
__device__ __forceinline__ void ktile(const unsigned short* __restrict__ pA,
                                      const unsigned short* __restrict__ pB,
                                      unsigned short* AsB, unsigned short* BsB,
                                      int kt, int w, int wm, int wn, int frow, int fk,
                                      f32x4 (&acc)[8][4]) {
  const unsigned short* Ac = AsB + BUF * (BM * BK);
  const unsigned short* Bc = BsB + BUF * (BN * BK);
  unsigned short* Aw = AsB + BUF * (BM * BK);        // tile t+2 -> cur buffer
  unsigned short* Bw = BsB + BUF * (BN * BK);
  unsigned short* An = AsB + (BUF ^ 1) * (BM * BK);  // tile t+1 last half

  bf16x8 bfrag[4][2];
  bf16x8 a0[2][2], a1[2][2], a2[2][2], a3[2][2];

  // ph0: read all B (8) + a0 (4); stage A1(t+1) -> other buffer
#pragma unroll
  for (int ni = 0; ni < 4; ++ni)
#pragma unroll
    for (int kk = 0; kk < 2; ++kk)
      bfrag[ni][kk] = lds_frag(Bc, wn * 64 + ni * 16 + frow, kk * 32 + fk);
  read_a(Ac, wm * 128 + 0, frow, fk, a0);
  if (MODE < 2) stage_half(pA, An, 128, kt + BK, w);
  __builtin_amdgcn_s_barrier();
  asm volatile("s_waitcnt lgkmcnt(0)" ::: "memory");
  mfma_quad(a0, bfrag, acc, 0);
  __builtin_amdgcn_s_barrier();

  // ph1: read a1; stage B0(t+2) (all B reads completed before ph0's closing barrier)
  read_a(Ac, wm * 128 + 32, frow, fk, a1);
  if (MODE == 0) stage_half(pB, Bw, 0, kt + 2 * BK, w);
  __builtin_amdgcn_s_barrier();
  asm volatile("s_waitcnt lgkmcnt(0)" ::: "memory");
  mfma_quad(a1, bfrag, acc, 2);
  __builtin_amdgcn_s_barrier();

  // ph2: read a2 AND a3; stage B1(t+2). lgkmcnt(0) completes a3 before the
  // closing barrier -> ph3's A0 stage cannot race any read of its region.
  read_a(Ac, wm * 128 + 64, frow, fk, a2);
  read_a(Ac, wm * 128 + 96, frow, fk, a3);
  if (MODE == 0) stage_half(pB, Bw, 128, kt + 2 * BK, w);
  __builtin_amdgcn_s_barrier();
  asm volatile("s_waitcnt lgkmcnt(0)" ::: "memory");
  mfma_quad(a2, bfrag, acc, 4);
  __builtin_amdgcn_s_barrier();

  // ph3: no reads; stage A0(t+2); counted vmcnt at tile boundary
  if (MODE == 0) stage_half(pA, Aw, 0, kt + 2 * BK, w);
  __builtin_amdgcn_s_barrier();
  mfma_quad(a3, bfrag, acc, 6);
  if (MODE == 0)
    asm volatile("s_waitcnt vmcnt(6)" ::: "memory");  // t+1 landed; t+2's 3 halves in flight
  else if (MODE == 1)
    asm volatile("s_waitcnt vmcnt(0)" ::: "memory");  // drain A1(NT-1)
  if (MODE < 2) __builtin_amdgcn_s_barrier();
}

__global__ __launch_bounds__(512, 2) void gemm256(const unsigned short* __restrict__ A,
                                                  const unsigned short* __restrict__ B,
                                                  const float* __restrict__ bias,
                                                  float* __restrict__ C) {
  __shared__ unsigned short AsB[2 * BM * BK];   // 64 KiB
  __shared__ unsigned short BsB[2 * BN * BK];   // 64 KiB

  const int tid = threadIdx.x;
  const int w = tid >> 6;
  const int l = tid & 63;
  const int wm = w >> 2;
  const int wn = w & 3;
  const int frow = l & 15;
  const int fk = (l >> 4) * 8;

  const int bid = blockIdx.x;
  const int cpx = gridDim.x >> 3;
  const int swz = (bid & 7) * cpx + (bid >> 3);
  const int bm0 = (swz >> 4) * BM;
  const int bn0 = (swz & 15) * BN;

  // lane-constant stage base pointers (scalar t*BK offset added per call)
  const int sr = l >> 3;
  const int skp = ((l & 7) ^ sr) << 3;
  const unsigned short* pA = A + (size_t)(bm0 + w * 16 + sr) * K_DIM + skp;
  const unsigned short* pB = B + (size_t)(bn0 + w * 16 + sr) * K_DIM + skp;

  f32x4 acc[8][4] = {};

  // Prologue: tile0 {B0,B1,A0,A1} -> buf0; tile1 {B0,B1,A0} -> buf1.
  stage_half(pB, BsB, 0, 0, w);
  stage_half(pB, BsB, 128, 0, w);
  stage_half(pA, AsB, 0, 0, w);
  stage_half(pA, AsB, 128, 0, w);
  stage_half(pB, BsB + BN * BK, 0, BK, w);
  stage_half(pB, BsB + BN * BK, 128, BK, w);
  stage_half(pA, AsB + BM * BK, 0, BK, w);
  asm volatile("s_waitcnt vmcnt(6)" ::: "memory");   // tile0 fully landed
  __builtin_amdgcn_s_barrier();

  // branch-free main loop: tiles 0 .. NT-3
  for (int t = 0; t < NT - 2; t += 2) {
    ktile<0, 0>(pA, pB, AsB, BsB, t * BK, w, wm, wn, frow, fk, acc);
    ktile<1, 0>(pA, pB, AsB, BsB, (t + 1) * BK, w, wm, wn, frow, fk, acc);
  }
  // peeled tail: tiles NT-2 (drain) and NT-1 (pure compute)
  ktile<0, 1>(pA, pB, AsB, BsB, (NT - 2) * BK, w, wm, wn, frow, fk, acc);
  ktile<1, 2>(pA, pB, AsB, BsB, (NT - 1) * BK, w, wm, wn, frow, fk, acc);

  // Epilogue: C/D layout col=lane&15 (n), row=(lane>>4)*4+r (m)
#pragma unroll
  for (int ni = 0; ni < 4; ++ni) {
    int n = bn0 + wn * 64 + ni * 16 + (l & 15);
    float bv = bias[n];
#pragma unroll
    for (int mi = 0; mi < 8; ++mi) {
      int mbase = bm0 + wm * 128 + mi * 16 + (l >> 4) * 4;
#pragma unroll
      for (int r = 0; r < 4; ++r)
        C[(size_t)(mbase + r) * N_DIM + n] = acc[mi][ni][r] + bv;
    }
  }
}

// ---------------- naive fallback ----------------

__global__ void naive_kernel(const float* __restrict__ x, const int* __restrict__ q,
                             const float* __restrict__ sc, const float* __restrict__ bias,
                             float* __restrict__ out) {
  size_t idx = (size_t)blockIdx.x * blockDim.x + threadIdx.x;
  if (idx >= (size_t)M_DIM * N_DIM) return;
  int n = (int)(idx & (N_DIM - 1));
  size_t m = idx >> 12;
  float acc = 0.f;
  for (int k = 0; k < K_DIM; k += 32) {
    float s = sc[n * NB_SC + (k >> 5)];
    float part = 0.f;
    for (int j = 0; j < 32; ++j)
      part += x[m * K_DIM + k + j] * (float)q[(size_t)n * K_DIM + k + j];
    acc += part * s;
  }
  out[idx] = acc + bias[n];
}

// ---------------- launch ----------------

extern "C" void kernel_launch(void* const* d_in, const int* in_sizes, int n_in,
                              void* d_out, int out_size, void* d_ws, size_t ws_size,
                              hipStream_t stream) {
  const float* x    = (const float*)d_in[0];
  const int*   q    = (const int*)d_in[1];
  const float* sc   = (const float*)d_in[2];
  const float* bias = (const float*)d_in[3];
  float* out = (float*)d_out;

  const size_t elems = (size_t)M_DIM * K_DIM;
  const size_t need  = 2 * elems * sizeof(unsigned short);

  if (ws_size >= need) {
    unsigned short* xb = (unsigned short*)d_ws;
    unsigned short* wb = xb + elems;
    hipLaunchKernelGGL(prep_kernel, dim3(4096), dim3(256), 0, stream, x, q, sc, xb, wb);
    hipLaunchKernelGGL(gemm256, dim3((M_DIM / BM) * (N_DIM / BN)), dim3(512), 0, stream,
                       xb, wb, bias, out);
  } else {
    hipLaunchKernelGGL(naive_kernel, dim3((M_DIM * N_DIM) / 256), dim3(256), 0, stream,
                       x, q, sc, bias, out);
  }
}